// Round 4
// baseline (390.345 us; speedup 1.0000x reference)
//
#include <hip/hip_runtime.h>
#include <math.h>

#define NTOK 2048      // B*S
#define DDIM 1024
#define HDIM 2048
#define NE 8
#define EPS_RMS 1e-5f
#define EPS_TOPK 1e-10f

#define KSPLIT 2
#define KCH (HDIM / KSPLIT)   // 1024

typedef short short8 __attribute__((ext_vector_type(8)));
typedef float f32x4  __attribute__((ext_vector_type(4)));

__device__ __forceinline__ unsigned pack2bf(float a, float b) {
    unsigned ua = __builtin_bit_cast(unsigned, a);
    unsigned ub = __builtin_bit_cast(unsigned, b);
    ua = (ua + 0x7fffu + ((ua >> 16) & 1u)) >> 16;
    ub = (ub + 0x7fffu + ((ub >> 16) & 1u)) & 0xffff0000u;
    return ua | ub;
}
__device__ __forceinline__ unsigned short f2bf(float a) {
    unsigned ua = __builtin_bit_cast(unsigned, a);
    return (unsigned short)((ua + 0x7fffu + ((ua >> 16) & 1u)) >> 16);
}

// async global->LDS, 16B per lane; lds base wave-uniform (lane i -> base + i*16)
__device__ __forceinline__ void gl2lds16(const unsigned short* g, unsigned short* l) {
    __builtin_amdgcn_global_load_lds(
        (const __attribute__((address_space(1))) unsigned int*)g,
        (__attribute__((address_space(3))) unsigned int*)l,
        16, 0, 0);
}

// ---------------- Kernel 0: fused RMSNorm/router + weight convert/transpose ----------------
// v4: BOTH memory directions copy-shaped (16B/lane, 1KB contiguous per wave-inst).
//   reads : float4, each wave-inst covers one full 1KB source-row segment
//   writes: uint4 into blocked layouts, each wave-inst 1KB contiguous
// (r0-r3 invariance: every prior version had at least one direction scalar/
//  fine-grain and all pinned at 1.6-2 TB/s = the documented scalar regime.)
// Blocked layouts (same as r3, GEMM-side unchanged):
//   wcat_blk[e][dc=d>>5][n][32]   n = (h>>5)*64 + mat*32 + (h&31)
//   w3_blk [e][hc=h>>5][d][32]
// Grid: 512 router + 2048 w1w2 + 2048 w3 = 4608 blocks, 256 threads.
__global__ __launch_bounds__(256) void k_prep4(
        const float* __restrict__ w1, const float* __restrict__ w2,
        const float* __restrict__ w3,
        unsigned short* __restrict__ wcatT,   // blocked [E][32][4096][32] bf16
        unsigned short* __restrict__ w3T,     // blocked [E][64][1024][32] bf16
        const float* __restrict__ x,
        const float* __restrict__ g,
        const float* __restrict__ gate_w,
        unsigned short* __restrict__ x_norm,
        int* __restrict__ counts,
        int* __restrict__ slot_token,
        float* __restrict__ slot_prob,
        int* __restrict__ tslot) {
    // bf16 stage [mat][32 k-rows][258 cols]; pad 258 (even: u32 stage writes stay
    // 4B-aligned). Stage writes <=4-way, readback <=2-way (free, m136).
    __shared__ unsigned short sst[2][32 * 258];   // 33024 B
    int tid = threadIdx.x;
    int bid = blockIdx.x;
    int wv = tid >> 6, l = tid & 63;

    if (bid >= 512 && bid < 2560) {
        // ---- w1+w2 -> wcat_blk: block = (e, d-chunk of 32, h-sect of 256) ----
        int idx = bid - 512;
        int e  = idx >> 8;
        int dc = (idx >> 3) & 31;
        int hs = idx & 7;
        int d0 = dc * 32, h0 = hs * 256;
        const float* b1 = w1 + (size_t)e * DDIM * HDIM + (size_t)d0 * HDIM + h0 + l * 4;
        const float* b2 = w2 + (size_t)e * DDIM * HDIM + (size_t)d0 * HDIM + h0 + l * 4;
        float4 va[8], vb[8];
        #pragma unroll
        for (int k = 0; k < 8; k++) va[k] = *(const float4*)(b1 + (size_t)(wv * 8 + k) * HDIM);
        #pragma unroll
        for (int k = 0; k < 8; k++) vb[k] = *(const float4*)(b2 + (size_t)(wv * 8 + k) * HDIM);
        #pragma unroll
        for (int k = 0; k < 8; k++) {
            int r = wv * 8 + k;
            unsigned* pa = (unsigned*)&sst[0][r * 258 + l * 4];
            pa[0] = pack2bf(va[k].x, va[k].y);
            pa[1] = pack2bf(va[k].z, va[k].w);
            unsigned* pb = (unsigned*)&sst[1][r * 258 + l * 4];
            pb[0] = pack2bf(vb[k].x, vb[k].y);
            pb[1] = pack2bf(vb[k].z, vb[k].w);
        }
        __syncthreads();
        // readback: pairs along d (row index); store 1KB contiguous per wave-inst
        size_t slab = ((size_t)(e * 32 + dc) * 4096 + (size_t)hs * 512) * 32;
        int rowin = (tid >> 2) & 31;
        int ul = tid & 3;
        int gh = tid >> 7;             // high half of block -> odd 2KB run
        #pragma unroll
        for (int j = 0; j < 4; j++) {
            int gg = 2 * j + gh;
            int hl = gg * 32 + rowin;
            #pragma unroll
            for (int m = 0; m < 2; m++) {
                const unsigned short* lp = &sst[m][0];
                uint4 W;
                unsigned short a0 = lp[(8 * ul + 0) * 258 + hl], a1 = lp[(8 * ul + 1) * 258 + hl];
                unsigned short a2 = lp[(8 * ul + 2) * 258 + hl], a3 = lp[(8 * ul + 3) * 258 + hl];
                unsigned short a4 = lp[(8 * ul + 4) * 258 + hl], a5 = lp[(8 * ul + 5) * 258 + hl];
                unsigned short a6 = lp[(8 * ul + 6) * 258 + hl], a7 = lp[(8 * ul + 7) * 258 + hl];
                W.x = (unsigned)a0 | ((unsigned)a1 << 16);
                W.y = (unsigned)a2 | ((unsigned)a3 << 16);
                W.z = (unsigned)a4 | ((unsigned)a5 << 16);
                W.w = (unsigned)a6 | ((unsigned)a7 << 16);
                size_t off = (size_t)gg * 2048 + (size_t)m * 1024 + rowin * 32 + ul * 8;  // u16 units
                *(uint4*)&wcatT[slab + off] = W;
            }
        }
        return;
    }
    if (bid >= 2560) {
        // ---- w3 -> w3_blk: block = (e, h-chunk of 32, d-sect of 256) ----
        int idx = bid - 2560;
        int e    = idx >> 8;
        int hc   = (idx & 255) >> 2;
        int dsec = idx & 3;
        int h0 = hc * 32, d0 = dsec * 256;
        const float* b3 = w3 + (size_t)e * HDIM * DDIM + (size_t)h0 * DDIM + d0 + l * 4;
        float4 va[8];
        #pragma unroll
        for (int k = 0; k < 8; k++) va[k] = *(const float4*)(b3 + (size_t)(wv * 8 + k) * DDIM);
        #pragma unroll
        for (int k = 0; k < 8; k++) {
            int r = wv * 8 + k;
            unsigned* pa = (unsigned*)&sst[0][r * 258 + l * 4];
            pa[0] = pack2bf(va[k].x, va[k].y);
            pa[1] = pack2bf(va[k].z, va[k].w);
        }
        __syncthreads();
        size_t slab = (((size_t)e * 64 + hc) * 1024 + d0) * 32;
        int ul = tid & 3;
        #pragma unroll
        for (int j = 0; j < 4; j++) {
            int dl = j * 64 + (tid >> 2);
            uint4 W;
            unsigned short a0 = sst[0][(8 * ul + 0) * 258 + dl], a1 = sst[0][(8 * ul + 1) * 258 + dl];
            unsigned short a2 = sst[0][(8 * ul + 2) * 258 + dl], a3 = sst[0][(8 * ul + 3) * 258 + dl];
            unsigned short a4 = sst[0][(8 * ul + 4) * 258 + dl], a5 = sst[0][(8 * ul + 5) * 258 + dl];
            unsigned short a6 = sst[0][(8 * ul + 6) * 258 + dl], a7 = sst[0][(8 * ul + 7) * 258 + dl];
            W.x = (unsigned)a0 | ((unsigned)a1 << 16);
            W.y = (unsigned)a2 | ((unsigned)a3 << 16);
            W.z = (unsigned)a4 | ((unsigned)a5 << 16);
            W.w = (unsigned)a6 | ((unsigned)a7 << 16);
            size_t off = (size_t)dl * 32 + ul * 8;   // u16 units
            *(uint4*)&w3T[slab + off] = W;
        }
        return;
    }

    // ---- router: RMSNorm + softmax top-2, one token per wave, 4 tokens/block ----
    int rid = bid;
    int lane = tid & 63;
    int token = rid * 4 + (tid >> 6);
    const float* xrow = x + (size_t)token * DDIM;

    float v[16];
    float ss = 0.f;
    #pragma unroll
    for (int i = 0; i < 16; i++) {
        float t = xrow[lane + i * 64];
        v[i] = t;
        ss += t * t;
    }
    #pragma unroll
    for (int o = 32; o > 0; o >>= 1) ss += __shfl_down(ss, o, 64);
    float scale = rsqrtf(__shfl(ss, 0, 64) * (1.f / (float)DDIM) + EPS_RMS);

    float part[NE];
    #pragma unroll
    for (int e = 0; e < NE; e++) part[e] = 0.f;
    #pragma unroll
    for (int i = 0; i < 16; i++) {
        int d = lane + i * 64;
        float xn = v[i] * scale * g[d];
        x_norm[(size_t)token * DDIM + d] = f2bf(xn);
        #pragma unroll
        for (int e = 0; e < NE; e++) part[e] += xn * gate_w[e * DDIM + d];
    }
    #pragma unroll
    for (int e = 0; e < NE; e++) {
        #pragma unroll
        for (int o = 32; o > 0; o >>= 1) part[e] += __shfl_down(part[e], o, 64);
    }

    if (lane == 0) {
        float mx = part[0];
        #pragma unroll
        for (int e = 1; e < NE; e++) mx = fmaxf(mx, part[e]);
        float p[NE];
        float Z = 0.f;
        #pragma unroll
        for (int e = 0; e < NE; e++) { p[e] = __expf(part[e] - mx); Z += p[e]; }
        float rz = 1.f / Z;
        #pragma unroll
        for (int e = 0; e < NE; e++) p[e] *= rz;
        int i1 = 0;
        #pragma unroll
        for (int e = 1; e < NE; e++) if (p[e] > p[i1]) i1 = e;
        int i2 = -1;
        #pragma unroll
        for (int e = 0; e < NE; e++) {
            if (e == i1) continue;
            if (i2 < 0 || p[e] > p[i2]) i2 = e;
        }
        float denom = p[i1] + p[i2] + EPS_TOPK;
        int pos1 = atomicAdd(&counts[i1], 1);
        slot_token[i1 * NTOK + pos1] = token;
        slot_prob[i1 * NTOK + pos1] = p[i1] / denom;
        tslot[token * 2 + 0] = i1 * NTOK + pos1;
        int pos2 = atomicAdd(&counts[i2], 1);
        slot_token[i2 * NTOK + pos2] = token;
        slot_prob[i2 * NTOK + pos2] = p[i2] / denom;
        tslot[token * 2 + 1] = i2 * NTOK + pos2;
    }
}

// ---------------- Kernel 2: gathered GEMM X @ [W1|W2] + fused SiLU -> hidden bf16 ----------------
// grid: (32, 16, NE), block 256 (4 waves, 2x2, each 64x64)
// 2-phase double-buffered pipeline: stage(t+1) issued BEFORE compute(t);
// one vmcnt(0)+barrier per K-step (guide T3 minimal recipe).
__global__ __launch_bounds__(256) void k_ffn_h(
        const unsigned short* __restrict__ x_norm,  // bf16 [NTOK][1024]
        const unsigned short* __restrict__ wcatT,   // blocked [E][32][4096][32]
        const int* __restrict__ counts,
        const int* __restrict__ slot_token,
        unsigned short* __restrict__ hidden) {      // bf16 [4096 slots][2048]
    int e = blockIdx.z;
    int cnt = counts[e];
    int m0 = blockIdx.y * 128;
    if (m0 >= cnt) return;
    int n0 = blockIdx.x * 128;
    int off = 0;
    for (int i = 0; i < e; i++) off += counts[i];

    int tid = threadIdx.x, lane = tid & 63, wv = tid >> 6;
    int l15 = lane & 15, q4 = lane >> 4;
    int wy = wv >> 1, wx = wv & 1;

    __shared__ unsigned short Ash[2][128 * 32];
    __shared__ unsigned short Bsh[2][128 * 32];
    __shared__ int tok[128];

    if (tid < 128) {
        int idx = m0 + tid;
        tok[tid] = (idx < cnt) ? slot_token[e * NTOK + idx] : slot_token[e * NTOK];
    }
    __syncthreads();

    int arow = wv * 32 + (lane >> 2);
    int t0 = tok[arow];
    int t1 = tok[arow + 16];
    const unsigned short* ag0 = x_norm + (size_t)t0 * DDIM + (lane & 3) * 8;
    const unsigned short* ag1 = x_norm + (size_t)t1 * DDIM + (lane & 3) * 8;
    const unsigned short* bg0 = wcatT + ((size_t)e * 32 * 4096 + (size_t)(n0 + arow)) * 32 + (lane & 3) * 8;

    f32x4 acc[4][4];
    #pragma unroll
    for (int i = 0; i < 4; i++)
        #pragma unroll
        for (int j = 0; j < 4; j++) acc[i][j] = (f32x4){0.f, 0.f, 0.f, 0.f};

    // prologue: stage tile 0 into buf 0
    gl2lds16(ag0, &Ash[0][wv * 1024]);
    gl2lds16(ag1, &Ash[0][wv * 1024 + 512]);
    gl2lds16(bg0, &Bsh[0][wv * 1024]);
    gl2lds16(bg0 + 16 * 32, &Bsh[0][wv * 1024 + 512]);
    __syncthreads();

    for (int it = 0; it < 32; ++it) {
        int cur = it & 1;
        if (it < 31) {
            int nx = cur ^ 1;
            const unsigned short* b = bg0 + (size_t)(it + 1) * 4096 * 32;
            gl2lds16(ag0 + (it + 1) * 32, &Ash[nx][wv * 1024]);
            gl2lds16(ag1 + (it + 1) * 32, &Ash[nx][wv * 1024 + 512]);
            gl2lds16(b, &Bsh[nx][wv * 1024]);
            gl2lds16(b + 16 * 32, &Bsh[nx][wv * 1024 + 512]);
        }
        short8 af[4], bf[4];
        #pragma unroll
        for (int i = 0; i < 4; i++) {
            af[i] = *(const short8*)&Ash[cur][(wy * 64 + i * 16 + l15) * 32 + q4 * 8];
            bf[i] = *(const short8*)&Bsh[cur][(wx * 64 + i * 16 + l15) * 32 + q4 * 8];
        }
        #pragma unroll
        for (int rf = 0; rf < 4; rf++)
            #pragma unroll
            for (int cf = 0; cf < 4; cf++)
                acc[rf][cf] = __builtin_amdgcn_mfma_f32_16x16x32_bf16(af[rf], bf[cf], acc[rf][cf], 0, 0, 0);
        __syncthreads();
    }

    // epilogue: cf 0,1 = w1 cols, cf 2,3 = w2 cols for the same h
    #pragma unroll
    for (int rf = 0; rf < 4; rf++) {
        int rowl = wy * 64 + rf * 16 + q4 * 4;
        #pragma unroll
        for (int hg = 0; hg < 2; hg++) {
            int h = (n0 >> 1) + wx * 32 + hg * 16 + l15;
            #pragma unroll
            for (int r = 0; r < 4; r++) {
                int rr = rowl + r;
                if (m0 + rr < cnt) {
                    float a = acc[rf][hg][r];
                    float b = acc[rf][hg + 2][r];
                    float hv = (a / (1.f + __expf(-a))) * b;
                    hidden[(size_t)(off + m0 + rr) * HDIM + h] = f2bf(hv);
                }
            }
        }
    }
}

// ---------------- Kernel 3: GEMM hidden @ w3_blk, K-split, 2-phase pipeline ----------------
// grid: (8, 16, NE*KSPLIT), block 256
__global__ __launch_bounds__(256) void k_ffn_out(
        const unsigned short* __restrict__ hidden,  // bf16 [4096][2048]
        const unsigned short* __restrict__ w3T,     // blocked [E][64][1024][32]
        const int* __restrict__ counts,
        float* __restrict__ yp) {                   // [KSPLIT][4096][1024] f32 partials
    int e = blockIdx.z >> 1;
    int ks = blockIdx.z & 1;
    int cnt = counts[e];
    int m0 = blockIdx.y * 128;
    if (m0 >= cnt) return;
    int d0 = blockIdx.x * 128;
    int off = 0;
    for (int i = 0; i < e; i++) off += counts[i];
    int hb = ks * KCH;

    int tid = threadIdx.x, lane = tid & 63, wv = tid >> 6;
    int l15 = lane & 15, q4 = lane >> 4;
    int wy = wv >> 1, wx = wv & 1;

    __shared__ unsigned short Ash[2][128 * 32];
    __shared__ unsigned short Bsh[2][128 * 32];

    int arow = wv * 32 + (lane >> 2);
    int s0 = off + ((m0 + arow < cnt) ? m0 + arow : 0);
    int s1 = off + ((m0 + arow + 16 < cnt) ? m0 + arow + 16 : 0);
    const unsigned short* ag0 = hidden + (size_t)s0 * HDIM + hb + (lane & 3) * 8;
    const unsigned short* ag1 = hidden + (size_t)s1 * HDIM + hb + (lane & 3) * 8;
    const unsigned short* bg0 = w3T + (((size_t)e * 64 + (hb >> 5)) * 1024 + (size_t)(d0 + arow)) * 32 + (lane & 3) * 8;

    f32x4 acc[4][4];
    #pragma unroll
    for (int i = 0; i < 4; i++)
        #pragma unroll
        for (int j = 0; j < 4; j++) acc[i][j] = (f32x4){0.f, 0.f, 0.f, 0.f};

    gl2lds16(ag0, &Ash[0][wv * 1024]);
    gl2lds16(ag1, &Ash[0][wv * 1024 + 512]);
    gl2lds16(bg0, &Bsh[0][wv * 1024]);
    gl2lds16(bg0 + 16 * 32, &Bsh[0][wv * 1024 + 512]);
    __syncthreads();

    for (int it = 0; it < 32; ++it) {
        int cur = it & 1;
        if (it < 31) {
            int nx = cur ^ 1;
            const unsigned short* b = bg0 + (size_t)(it + 1) * 1024 * 32;
            gl2lds16(ag0 + (it + 1) * 32, &Ash[nx][wv * 1024]);
            gl2lds16(ag1 + (it + 1) * 32, &Ash[nx][wv * 1024 + 512]);
            gl2lds16(b, &Bsh[nx][wv * 1024]);
            gl2lds16(b + 16 * 32, &Bsh[nx][wv * 1024 + 512]);
        }
        short8 af[4], bf[4];
        #pragma unroll
        for (int i = 0; i < 4; i++) {
            af[i] = *(const short8*)&Ash[cur][(wy * 64 + i * 16 + l15) * 32 + q4 * 8];
            bf[i] = *(const short8*)&Bsh[cur][(wx * 64 + i * 16 + l15) * 32 + q4 * 8];
        }
        #pragma unroll
        for (int rf = 0; rf < 4; rf++)
            #pragma unroll
            for (int cf = 0; cf < 4; cf++)
                acc[rf][cf] = __builtin_amdgcn_mfma_f32_16x16x32_bf16(af[rf], bf[cf], acc[rf][cf], 0, 0, 0);
        __syncthreads();
    }

    float* ypk = yp + (size_t)ks * 4096 * 1024;
    #pragma unroll
    for (int rf = 0; rf < 4; rf++) {
        int rowl = wy * 64 + rf * 16 + q4 * 4;
        #pragma unroll
        for (int cf = 0; cf < 4; cf++) {
            int col = d0 + wx * 64 + cf * 16 + l15;
            #pragma unroll
            for (int r = 0; r < 4; r++) {
                int rr = rowl + r;
                if (m0 + rr < cnt) {
                    ypk[(size_t)(off + m0 + rr) * 1024 + col] = acc[rf][cf][r];
                }
            }
        }
    }
}

// ---------------- Kernel 4: gather partials -> out ----------------
// grid NTOK/2, block 256; each half-block does one token row (1024 f32)
__global__ __launch_bounds__(256) void k_gather(
        const float* __restrict__ yp,         // [KSPLIT][4096][1024]
        const int* __restrict__ counts,
        const int* __restrict__ tslot,
        const float* __restrict__ slot_prob,
        float* __restrict__ out) {
    __shared__ int offs[NE];
    int tid = threadIdx.x;
    if (tid < NE) {
        int o = 0;
        for (int i = 0; i < tid; i++) o += counts[i];
        offs[tid] = o;
    }
    __syncthreads();

    int token = blockIdx.x * 2 + (tid >> 7);
    int col = (tid & 127) * 8;

    int s0 = tslot[token * 2], s1 = tslot[token * 2 + 1];
    int g0 = offs[s0 / NTOK] + (s0 % NTOK);
    int g1 = offs[s1 / NTOK] + (s1 % NTOK);
    float pr0 = slot_prob[s0], pr1 = slot_prob[s1];

    const float* p00 = yp + (size_t)g0 * 1024 + col;
    const float* p01 = yp + (size_t)(4096 + g0) * 1024 + col;
    const float* p10 = yp + (size_t)g1 * 1024 + col;
    const float* p11 = yp + (size_t)(4096 + g1) * 1024 + col;
    float* op = out + (size_t)token * 1024 + col;

    #pragma unroll
    for (int v = 0; v < 2; v++) {
        float4 a0 = *(const float4*)(p00 + v * 4);
        float4 a1 = *(const float4*)(p01 + v * 4);
        float4 b0 = *(const float4*)(p10 + v * 4);
        float4 b1 = *(const float4*)(p11 + v * 4);
        float4 r;
        r.x = pr0 * (a0.x + a1.x) + pr1 * (b0.x + b1.x);
        r.y = pr0 * (a0.y + a1.y) + pr1 * (b0.y + b1.y);
        r.z = pr0 * (a0.z + a1.z) + pr1 * (b0.z + b1.z);
        r.w = pr0 * (a0.w + a1.w) + pr1 * (b0.w + b1.w);
        *(float4*)(op + v * 4) = r;
    }
}

// ---------------- launch ----------------
extern "C" void kernel_launch(void* const* d_in, const int* in_sizes, int n_in,
                              void* d_out, int out_size, void* d_ws, size_t ws_size,
                              hipStream_t stream) {
    const float* x      = (const float*)d_in[0];
    const float* g      = (const float*)d_in[1];
    const float* gate_w = (const float*)d_in[2];
    const float* w1     = (const float*)d_in[3];
    const float* w2     = (const float*)d_in[4];
    const float* w3     = (const float*)d_in[5];
    float* out = (float*)d_out;

    char* ws = (char*)d_ws;
    int*   counts     = (int*)ws;                 ws += 256;
    int*   slot_token = (int*)ws;                 ws += NE * NTOK * 4;
    float* slot_prob  = (float*)ws;               ws += NE * NTOK * 4;
    int*   tslot      = (int*)ws;                 ws += NTOK * 2 * 4;
    unsigned short* x_norm = (unsigned short*)ws; ws += (size_t)NTOK * DDIM * 2;           // 4 MB
    unsigned short* hidden = (unsigned short*)ws; ws += (size_t)NTOK * 2 * HDIM * 2;       // 16 MB
    unsigned short* wcatT  = (unsigned short*)ws; ws += (size_t)NE * 4096 * 1024 * 2;      // 64 MB (blocked)
    unsigned short* w3T    = (unsigned short*)ws; ws += (size_t)NE * 1024 * 2048 * 2;      // 32 MB (blocked)
    float* yp              = (float*)ws;          ws += (size_t)KSPLIT * 4096 * 1024 * 4;  // 32 MB

    hipMemsetAsync(counts, 0, 256, stream);

    // 512 router + 2048 w1w2 + 2048 w3 blocks
    k_prep4<<<dim3(512 + 2048 + 2048), 256, 0, stream>>>(
        w1, w2, w3, wcatT, w3T, x, g, gate_w, x_norm, counts, slot_token, slot_prob, tslot);

    dim3 grid_h(4096 / 128, NTOK / 128, NE);
    k_ffn_h<<<grid_h, 256, 0, stream>>>(x_norm, wcatT, counts, slot_token, hidden);

    dim3 grid_o(1024 / 128, NTOK / 128, NE * KSPLIT);
    k_ffn_out<<<grid_o, 256, 0, stream>>>(hidden, w3T, counts, yp);

    k_gather<<<NTOK / 2, 256, 0, stream>>>(yp, counts, tslot, slot_prob, out);
}

// Round 5
// 384.920 us; speedup vs baseline: 1.0141x; 1.0141x over previous
//
#include <hip/hip_runtime.h>
#include <math.h>

#define NTOK 2048      // B*S
#define DDIM 1024
#define HDIM 2048
#define NE 8
#define EPS_RMS 1e-5f
#define EPS_TOPK 1e-10f

#define KSPLIT 2
#define KCH (HDIM / KSPLIT)   // 1024

// flat m-tiles over the concatenated slot array (always exactly 4096 slots);
// worst case sum_e ceil(cnt_e/128) <= 32 + 7 = 39
#define MT_MAX 40

typedef short short8 __attribute__((ext_vector_type(8)));
typedef float f32x4  __attribute__((ext_vector_type(4)));

__device__ __forceinline__ unsigned pack2bf(float a, float b) {
    unsigned ua = __builtin_bit_cast(unsigned, a);
    unsigned ub = __builtin_bit_cast(unsigned, b);
    ua = (ua + 0x7fffu + ((ua >> 16) & 1u)) >> 16;
    ub = (ub + 0x7fffu + ((ub >> 16) & 1u)) & 0xffff0000u;
    return ua | ub;
}
__device__ __forceinline__ unsigned short f2bf(float a) {
    unsigned ua = __builtin_bit_cast(unsigned, a);
    return (unsigned short)((ua + 0x7fffu + ((ua >> 16) & 1u)) >> 16);
}

// async global->LDS, 16B per lane; lds base wave-uniform (lane i -> base + i*16)
__device__ __forceinline__ void gl2lds16(const unsigned short* g, unsigned short* l) {
    __builtin_amdgcn_global_load_lds(
        (const __attribute__((address_space(1))) unsigned int*)g,
        (__attribute__((address_space(3))) unsigned int*)l,
        16, 0, 0);
}

// ---------------- Kernel 0: fused RMSNorm/router + weight convert/transpose ----------------
// (unchanged from r4 — four structurally different prep versions all pinned at
//  ~129 us / 1.6 TB/s, so prep micro-structure is not the lever; keep the version
//  that feeds the blocked GEMM layout.)
// Blocked layouts:
//   wcat_blk[e][dc=d>>5][n][32]   n = (h>>5)*64 + mat*32 + (h&31)
//   w3_blk [e][hc=h>>5][d][32]
__global__ __launch_bounds__(256) void k_prep4(
        const float* __restrict__ w1, const float* __restrict__ w2,
        const float* __restrict__ w3,
        unsigned short* __restrict__ wcatT,   // blocked [E][32][4096][32] bf16
        unsigned short* __restrict__ w3T,     // blocked [E][64][1024][32] bf16
        const float* __restrict__ x,
        const float* __restrict__ g,
        const float* __restrict__ gate_w,
        unsigned short* __restrict__ x_norm,
        int* __restrict__ counts,
        int* __restrict__ slot_token,
        float* __restrict__ slot_prob,
        int* __restrict__ tslot) {
    __shared__ unsigned short sst[2][32 * 258];   // 33024 B
    int tid = threadIdx.x;
    int bid = blockIdx.x;
    int wv = tid >> 6, l = tid & 63;

    if (bid >= 512 && bid < 2560) {
        // ---- w1+w2 -> wcat_blk: block = (e, d-chunk of 32, h-sect of 256) ----
        int idx = bid - 512;
        int e  = idx >> 8;
        int dc = (idx >> 3) & 31;
        int hs = idx & 7;
        int d0 = dc * 32, h0 = hs * 256;
        const float* b1 = w1 + (size_t)e * DDIM * HDIM + (size_t)d0 * HDIM + h0 + l * 4;
        const float* b2 = w2 + (size_t)e * DDIM * HDIM + (size_t)d0 * HDIM + h0 + l * 4;
        float4 va[8], vb[8];
        #pragma unroll
        for (int k = 0; k < 8; k++) va[k] = *(const float4*)(b1 + (size_t)(wv * 8 + k) * HDIM);
        #pragma unroll
        for (int k = 0; k < 8; k++) vb[k] = *(const float4*)(b2 + (size_t)(wv * 8 + k) * HDIM);
        #pragma unroll
        for (int k = 0; k < 8; k++) {
            int r = wv * 8 + k;
            unsigned* pa = (unsigned*)&sst[0][r * 258 + l * 4];
            pa[0] = pack2bf(va[k].x, va[k].y);
            pa[1] = pack2bf(va[k].z, va[k].w);
            unsigned* pb = (unsigned*)&sst[1][r * 258 + l * 4];
            pb[0] = pack2bf(vb[k].x, vb[k].y);
            pb[1] = pack2bf(vb[k].z, vb[k].w);
        }
        __syncthreads();
        size_t slab = ((size_t)(e * 32 + dc) * 4096 + (size_t)hs * 512) * 32;
        int rowin = (tid >> 2) & 31;
        int ul = tid & 3;
        int gh = tid >> 7;
        #pragma unroll
        for (int j = 0; j < 4; j++) {
            int gg = 2 * j + gh;
            int hl = gg * 32 + rowin;
            #pragma unroll
            for (int m = 0; m < 2; m++) {
                const unsigned short* lp = &sst[m][0];
                uint4 W;
                unsigned short a0 = lp[(8 * ul + 0) * 258 + hl], a1 = lp[(8 * ul + 1) * 258 + hl];
                unsigned short a2 = lp[(8 * ul + 2) * 258 + hl], a3 = lp[(8 * ul + 3) * 258 + hl];
                unsigned short a4 = lp[(8 * ul + 4) * 258 + hl], a5 = lp[(8 * ul + 5) * 258 + hl];
                unsigned short a6 = lp[(8 * ul + 6) * 258 + hl], a7 = lp[(8 * ul + 7) * 258 + hl];
                W.x = (unsigned)a0 | ((unsigned)a1 << 16);
                W.y = (unsigned)a2 | ((unsigned)a3 << 16);
                W.z = (unsigned)a4 | ((unsigned)a5 << 16);
                W.w = (unsigned)a6 | ((unsigned)a7 << 16);
                size_t off = (size_t)gg * 2048 + (size_t)m * 1024 + rowin * 32 + ul * 8;
                *(uint4*)&wcatT[slab + off] = W;
            }
        }
        return;
    }
    if (bid >= 2560) {
        // ---- w3 -> w3_blk: block = (e, h-chunk of 32, d-sect of 256) ----
        int idx = bid - 2560;
        int e    = idx >> 8;
        int hc   = (idx & 255) >> 2;
        int dsec = idx & 3;
        int h0 = hc * 32, d0 = dsec * 256;
        const float* b3 = w3 + (size_t)e * HDIM * DDIM + (size_t)h0 * DDIM + d0 + l * 4;
        float4 va[8];
        #pragma unroll
        for (int k = 0; k < 8; k++) va[k] = *(const float4*)(b3 + (size_t)(wv * 8 + k) * DDIM);
        #pragma unroll
        for (int k = 0; k < 8; k++) {
            int r = wv * 8 + k;
            unsigned* pa = (unsigned*)&sst[0][r * 258 + l * 4];
            pa[0] = pack2bf(va[k].x, va[k].y);
            pa[1] = pack2bf(va[k].z, va[k].w);
        }
        __syncthreads();
        size_t slab = (((size_t)e * 64 + hc) * 1024 + d0) * 32;
        int ul = tid & 3;
        #pragma unroll
        for (int j = 0; j < 4; j++) {
            int dl = j * 64 + (tid >> 2);
            uint4 W;
            unsigned short a0 = sst[0][(8 * ul + 0) * 258 + dl], a1 = sst[0][(8 * ul + 1) * 258 + dl];
            unsigned short a2 = sst[0][(8 * ul + 2) * 258 + dl], a3 = sst[0][(8 * ul + 3) * 258 + dl];
            unsigned short a4 = sst[0][(8 * ul + 4) * 258 + dl], a5 = sst[0][(8 * ul + 5) * 258 + dl];
            unsigned short a6 = sst[0][(8 * ul + 6) * 258 + dl], a7 = sst[0][(8 * ul + 7) * 258 + dl];
            W.x = (unsigned)a0 | ((unsigned)a1 << 16);
            W.y = (unsigned)a2 | ((unsigned)a3 << 16);
            W.z = (unsigned)a4 | ((unsigned)a5 << 16);
            W.w = (unsigned)a6 | ((unsigned)a7 << 16);
            size_t off = (size_t)dl * 32 + ul * 8;
            *(uint4*)&w3T[slab + off] = W;
        }
        return;
    }

    // ---- router: RMSNorm + softmax top-2, one token per wave, 4 tokens/block ----
    int rid = bid;
    int lane = tid & 63;
    int token = rid * 4 + (tid >> 6);
    const float* xrow = x + (size_t)token * DDIM;

    float v[16];
    float ss = 0.f;
    #pragma unroll
    for (int i = 0; i < 16; i++) {
        float t = xrow[lane + i * 64];
        v[i] = t;
        ss += t * t;
    }
    #pragma unroll
    for (int o = 32; o > 0; o >>= 1) ss += __shfl_down(ss, o, 64);
    float scale = rsqrtf(__shfl(ss, 0, 64) * (1.f / (float)DDIM) + EPS_RMS);

    float part[NE];
    #pragma unroll
    for (int e = 0; e < NE; e++) part[e] = 0.f;
    #pragma unroll
    for (int i = 0; i < 16; i++) {
        int d = lane + i * 64;
        float xn = v[i] * scale * g[d];
        x_norm[(size_t)token * DDIM + d] = f2bf(xn);
        #pragma unroll
        for (int e = 0; e < NE; e++) part[e] += xn * gate_w[e * DDIM + d];
    }
    #pragma unroll
    for (int e = 0; e < NE; e++) {
        #pragma unroll
        for (int o = 32; o > 0; o >>= 1) part[e] += __shfl_down(part[e], o, 64);
    }

    if (lane == 0) {
        float mx = part[0];
        #pragma unroll
        for (int e = 1; e < NE; e++) mx = fmaxf(mx, part[e]);
        float p[NE];
        float Z = 0.f;
        #pragma unroll
        for (int e = 0; e < NE; e++) { p[e] = __expf(part[e] - mx); Z += p[e]; }
        float rz = 1.f / Z;
        #pragma unroll
        for (int e = 0; e < NE; e++) p[e] *= rz;
        int i1 = 0;
        #pragma unroll
        for (int e = 1; e < NE; e++) if (p[e] > p[i1]) i1 = e;
        int i2 = -1;
        #pragma unroll
        for (int e = 0; e < NE; e++) {
            if (e == i1) continue;
            if (i2 < 0 || p[e] > p[i2]) i2 = e;
        }
        float denom = p[i1] + p[i2] + EPS_TOPK;
        int pos1 = atomicAdd(&counts[i1], 1);
        slot_token[i1 * NTOK + pos1] = token;
        slot_prob[i1 * NTOK + pos1] = p[i1] / denom;
        tslot[token * 2 + 0] = i1 * NTOK + pos1;
        int pos2 = atomicAdd(&counts[i2], 1);
        slot_token[i2 * NTOK + pos2] = token;
        slot_prob[i2 * NTOK + pos2] = p[i2] / denom;
        tslot[token * 2 + 1] = i2 * NTOK + pos2;
    }
}

// map flat m-tile t (over concatenated slot array) -> (expert e, tile-local m0,
// slot offset off). Returns false if t beyond the last tile.
__device__ __forceinline__ bool flat_tile(const int* counts, int t,
                                          int& e, int& m0, int& off, int& cnt) {
    off = 0;
    for (e = 0; e < NE; e++) {
        cnt = counts[e];
        int nt = (cnt + 127) >> 7;
        if (t < nt) { m0 = t * 128; return true; }
        t -= nt;
        off += cnt;
    }
    return false;
}

// ---------------- Kernel 2: gathered GEMM X @ [W1|W2] + fused SiLU -> hidden bf16 ----------------
// 1-D grid 8*4*MT_MAX = 1280, block 256 (4 waves, 2x2, each 64x64).
// XCD-owned n-tiles (T1): xcd = bid&7 owns n-tiles xcd*4..xcd*4+3; its m-tiles
// run consecutively, so each 256KB B-tile is read from L3 once then re-read
// from that XCD's L2 (was: 16x from L3, ~1 GB total -> now ~64 MB).
// Flat m-tiles over the 4096-slot array kill the 75% dead blocks.
__global__ __launch_bounds__(256) void k_ffn_h(
        const unsigned short* __restrict__ x_norm,  // bf16 [NTOK][1024]
        const unsigned short* __restrict__ wcatT,   // blocked [E][32][4096][32]
        const int* __restrict__ counts,
        const int* __restrict__ slot_token,
        unsigned short* __restrict__ hidden) {      // bf16 [4096 slots][2048]
    int bid = blockIdx.x;
    int xcd = bid & 7;
    int idx = bid >> 3;               // 0..159
    int nn = idx / MT_MAX;            // 0..3
    int mt = idx % MT_MAX;
    int n0 = (xcd * 4 + nn) * 128;

    int e, m0, off, cnt;
    if (!flat_tile(counts, mt, e, m0, off, cnt)) return;

    int tid = threadIdx.x, lane = tid & 63, wv = tid >> 6;
    int l15 = lane & 15, q4 = lane >> 4;
    int wy = wv >> 1, wx = wv & 1;

    __shared__ unsigned short Ash[128 * 32];
    __shared__ unsigned short Bsh[128 * 32];
    __shared__ int tok[128];

    if (tid < 128) {
        int i = m0 + tid;
        tok[tid] = (i < cnt) ? slot_token[e * NTOK + i] : slot_token[e * NTOK];
    }
    __syncthreads();

    int arow = wv * 32 + (lane >> 2);
    int t0 = tok[arow];
    int t1 = tok[arow + 16];
    const unsigned short* ag0 = x_norm + (size_t)t0 * DDIM + (lane & 3) * 8;
    const unsigned short* ag1 = x_norm + (size_t)t1 * DDIM + (lane & 3) * 8;
    const unsigned short* bg0 = wcatT + ((size_t)e * 32 * 4096 + (size_t)(n0 + arow)) * 32 + (lane & 3) * 8;
    const unsigned short* bg1 = bg0 + 16 * 32;
    unsigned short* alds = &Ash[wv * 1024];
    unsigned short* blds = &Bsh[wv * 1024];

    f32x4 acc[4][4];
    #pragma unroll
    for (int i = 0; i < 4; i++)
        #pragma unroll
        for (int j = 0; j < 4; j++) acc[i][j] = (f32x4){0.f, 0.f, 0.f, 0.f};

    for (int d0 = 0; d0 < DDIM; d0 += 32) {
        __syncthreads();
        gl2lds16(ag0 + d0, alds);
        gl2lds16(ag1 + d0, alds + 512);
        gl2lds16(bg0, blds);
        gl2lds16(bg1, blds + 512);
        bg0 += 4096 * 32;   // next d-chunk slab
        bg1 += 4096 * 32;
        __syncthreads();

        short8 af[4], bf[4];
        #pragma unroll
        for (int i = 0; i < 4; i++) {
            af[i] = *(const short8*)&Ash[(wy * 64 + i * 16 + l15) * 32 + q4 * 8];
            bf[i] = *(const short8*)&Bsh[(wx * 64 + i * 16 + l15) * 32 + q4 * 8];
        }
        #pragma unroll
        for (int rf = 0; rf < 4; rf++)
            #pragma unroll
            for (int cf = 0; cf < 4; cf++)
                acc[rf][cf] = __builtin_amdgcn_mfma_f32_16x16x32_bf16(af[rf], bf[cf], acc[rf][cf], 0, 0, 0);
    }

    // epilogue: cf 0,1 = w1 cols, cf 2,3 = w2 cols for the same h
    #pragma unroll
    for (int rf = 0; rf < 4; rf++) {
        int rowl = wy * 64 + rf * 16 + q4 * 4;
        #pragma unroll
        for (int hg = 0; hg < 2; hg++) {
            int h = (n0 >> 1) + wx * 32 + hg * 16 + l15;
            #pragma unroll
            for (int r = 0; r < 4; r++) {
                int rr = rowl + r;
                if (m0 + rr < cnt) {
                    float a = acc[rf][hg][r];
                    float b = acc[rf][hg + 2][r];
                    float hv = (a / (1.f + __expf(-a))) * b;
                    hidden[(size_t)(off + m0 + rr) * HDIM + h] = f2bf(hv);
                }
            }
        }
    }
}

// ---------------- Kernel 3: GEMM hidden @ w3_blk, K-split ----------------
// 1-D grid 8*2*MT_MAX = 640. xcd = bid&7 owns d-tile xcd (one 256KB B-tile per
// (e,ks) stays L2-resident across its consecutive m-tiles).
__global__ __launch_bounds__(256) void k_ffn_out(
        const unsigned short* __restrict__ hidden,  // bf16 [4096][2048]
        const unsigned short* __restrict__ w3T,     // blocked [E][64][1024][32]
        const int* __restrict__ counts,
        float* __restrict__ yp) {                   // [KSPLIT][4096][1024] f32 partials
    int bid = blockIdx.x;
    int xcd = bid & 7;
    int idx = bid >> 3;               // 0..79
    int ks = idx / MT_MAX;            // 0..1
    int mt = idx % MT_MAX;
    int d0 = xcd * 128;

    int e, m0, off, cnt;
    if (!flat_tile(counts, mt, e, m0, off, cnt)) return;
    int hb = ks * KCH;

    int tid = threadIdx.x, lane = tid & 63, wv = tid >> 6;
    int l15 = lane & 15, q4 = lane >> 4;
    int wy = wv >> 1, wx = wv & 1;

    __shared__ unsigned short Ash[128 * 32];
    __shared__ unsigned short Bsh[128 * 32];

    int arow = wv * 32 + (lane >> 2);
    int s0 = off + ((m0 + arow < cnt) ? m0 + arow : 0);
    int s1 = off + ((m0 + arow + 16 < cnt) ? m0 + arow + 16 : 0);
    const unsigned short* ag0 = hidden + (size_t)s0 * HDIM + hb + (lane & 3) * 8;
    const unsigned short* ag1 = hidden + (size_t)s1 * HDIM + hb + (lane & 3) * 8;
    const unsigned short* bg0 = w3T + (((size_t)e * 64 + (hb >> 5)) * 1024 + (size_t)(d0 + arow)) * 32 + (lane & 3) * 8;
    const unsigned short* bg1 = bg0 + 16 * 32;
    unsigned short* alds = &Ash[wv * 1024];
    unsigned short* blds = &Bsh[wv * 1024];

    f32x4 acc[4][4];
    #pragma unroll
    for (int i = 0; i < 4; i++)
        #pragma unroll
        for (int j = 0; j < 4; j++) acc[i][j] = (f32x4){0.f, 0.f, 0.f, 0.f};

    for (int h0 = 0; h0 < KCH; h0 += 32) {
        __syncthreads();
        gl2lds16(ag0 + h0, alds);
        gl2lds16(ag1 + h0, alds + 512);
        gl2lds16(bg0, blds);
        gl2lds16(bg1, blds + 512);
        bg0 += 1024 * 32;   // next h-chunk slab
        bg1 += 1024 * 32;
        __syncthreads();

        short8 af[4], bf[4];
        #pragma unroll
        for (int i = 0; i < 4; i++) {
            af[i] = *(const short8*)&Ash[(wy * 64 + i * 16 + l15) * 32 + q4 * 8];
            bf[i] = *(const short8*)&Bsh[(wx * 64 + i * 16 + l15) * 32 + q4 * 8];
        }
        #pragma unroll
        for (int rf = 0; rf < 4; rf++)
            #pragma unroll
            for (int cf = 0; cf < 4; cf++)
                acc[rf][cf] = __builtin_amdgcn_mfma_f32_16x16x32_bf16(af[rf], bf[cf], acc[rf][cf], 0, 0, 0);
    }

    float* ypk = yp + (size_t)ks * 4096 * 1024;
    #pragma unroll
    for (int rf = 0; rf < 4; rf++) {
        int rowl = wy * 64 + rf * 16 + q4 * 4;
        #pragma unroll
        for (int cf = 0; cf < 4; cf++) {
            int col = d0 + wx * 64 + cf * 16 + l15;
            #pragma unroll
            for (int r = 0; r < 4; r++) {
                int rr = rowl + r;
                if (m0 + rr < cnt) {
                    ypk[(size_t)(off + m0 + rr) * 1024 + col] = acc[rf][cf][r];
                }
            }
        }
    }
}

// ---------------- Kernel 4: gather partials -> out ----------------
// grid NTOK/2, block 256; each half-block does one token row (1024 f32)
__global__ __launch_bounds__(256) void k_gather(
        const float* __restrict__ yp,         // [KSPLIT][4096][1024]
        const int* __restrict__ counts,
        const int* __restrict__ tslot,
        const float* __restrict__ slot_prob,
        float* __restrict__ out) {
    __shared__ int offs[NE];
    int tid = threadIdx.x;
    if (tid < NE) {
        int o = 0;
        for (int i = 0; i < tid; i++) o += counts[i];
        offs[tid] = o;
    }
    __syncthreads();

    int token = blockIdx.x * 2 + (tid >> 7);
    int col = (tid & 127) * 8;

    int s0 = tslot[token * 2], s1 = tslot[token * 2 + 1];
    int g0 = offs[s0 / NTOK] + (s0 % NTOK);
    int g1 = offs[s1 / NTOK] + (s1 % NTOK);
    float pr0 = slot_prob[s0], pr1 = slot_prob[s1];

    const float* p00 = yp + (size_t)g0 * 1024 + col;
    const float* p01 = yp + (size_t)(4096 + g0) * 1024 + col;
    const float* p10 = yp + (size_t)g1 * 1024 + col;
    const float* p11 = yp + (size_t)(4096 + g1) * 1024 + col;
    float* op = out + (size_t)token * 1024 + col;

    #pragma unroll
    for (int v = 0; v < 2; v++) {
        float4 a0 = *(const float4*)(p00 + v * 4);
        float4 a1 = *(const float4*)(p01 + v * 4);
        float4 b0 = *(const float4*)(p10 + v * 4);
        float4 b1 = *(const float4*)(p11 + v * 4);
        float4 r;
        r.x = pr0 * (a0.x + a1.x) + pr1 * (b0.x + b1.x);
        r.y = pr0 * (a0.y + a1.y) + pr1 * (b0.y + b1.y);
        r.z = pr0 * (a0.z + a1.z) + pr1 * (b0.z + b1.z);
        r.w = pr0 * (a0.w + a1.w) + pr1 * (b0.w + b1.w);
        *(float4*)(op + v * 4) = r;
    }
}

// ---------------- launch ----------------
extern "C" void kernel_launch(void* const* d_in, const int* in_sizes, int n_in,
                              void* d_out, int out_size, void* d_ws, size_t ws_size,
                              hipStream_t stream) {
    const float* x      = (const float*)d_in[0];
    const float* g      = (const float*)d_in[1];
    const float* gate_w = (const float*)d_in[2];
    const float* w1     = (const float*)d_in[3];
    const float* w2     = (const float*)d_in[4];
    const float* w3     = (const float*)d_in[5];
    float* out = (float*)d_out;

    char* ws = (char*)d_ws;
    int*   counts     = (int*)ws;                 ws += 256;
    int*   slot_token = (int*)ws;                 ws += NE * NTOK * 4;
    float* slot_prob  = (float*)ws;               ws += NE * NTOK * 4;
    int*   tslot      = (int*)ws;                 ws += NTOK * 2 * 4;
    unsigned short* x_norm = (unsigned short*)ws; ws += (size_t)NTOK * DDIM * 2;           // 4 MB
    unsigned short* hidden = (unsigned short*)ws; ws += (size_t)NTOK * 2 * HDIM * 2;       // 16 MB
    unsigned short* wcatT  = (unsigned short*)ws; ws += (size_t)NE * 4096 * 1024 * 2;      // 64 MB (blocked)
    unsigned short* w3T    = (unsigned short*)ws; ws += (size_t)NE * 1024 * 2048 * 2;      // 32 MB (blocked)
    float* yp              = (float*)ws;          ws += (size_t)KSPLIT * 4096 * 1024 * 4;  // 32 MB

    hipMemsetAsync(counts, 0, 256, stream);

    // 512 router + 2048 w1w2 + 2048 w3 blocks
    k_prep4<<<dim3(512 + 2048 + 2048), 256, 0, stream>>>(
        w1, w2, w3, wcatT, w3T, x, g, gate_w, x_norm, counts, slot_token, slot_prob, tslot);

    // XCD-owned n-tiles + flat m-tiles
    k_ffn_h<<<dim3(8 * 4 * MT_MAX), 256, 0, stream>>>(x_norm, wcatT, counts, slot_token, hidden);

    k_ffn_out<<<dim3(8 * 2 * MT_MAX), 256, 0, stream>>>(hidden, w3T, counts, yp);

    k_gather<<<NTOK / 2, 256, 0, stream>>>(yp, counts, tslot, slot_prob, out);
}

// Round 6
// 383.561 us; speedup vs baseline: 1.0177x; 1.0035x over previous
//
#include <hip/hip_runtime.h>
#include <math.h>

#define NTOK 2048      // B*S
#define DDIM 1024
#define HDIM 2048
#define NE 8
#define EPS_RMS 1e-5f
#define EPS_TOPK 1e-10f

#define KSPLIT 2
#define KCH (HDIM / KSPLIT)   // 1024

// flat m-tiles over the concatenated slot array (always exactly 4096 slots);
// worst case sum_e ceil(cnt_e/128) <= 32 + 7 = 39
#define MT_MAX 40
#define NGEMM (8 * 4 * MT_MAX)   // 1280 GEMM blocks in k_ffn_h5

typedef short short8 __attribute__((ext_vector_type(8)));
typedef float f32x4  __attribute__((ext_vector_type(4)));

__device__ __forceinline__ unsigned pack2bf(float a, float b) {
    unsigned ua = __builtin_bit_cast(unsigned, a);
    unsigned ub = __builtin_bit_cast(unsigned, b);
    ua = (ua + 0x7fffu + ((ua >> 16) & 1u)) >> 16;
    ub = (ub + 0x7fffu + ((ub >> 16) & 1u)) & 0xffff0000u;
    return ua | ub;
}
__device__ __forceinline__ unsigned short f2bf(float a) {
    unsigned ua = __builtin_bit_cast(unsigned, a);
    return (unsigned short)((ua + 0x7fffu + ((ua >> 16) & 1u)) >> 16);
}
// hw packed fp32x2 -> bf16x2 (RNE); guide T12: no builtin on gfx950, use asm
__device__ __forceinline__ unsigned cvtpk(float lo, float hi) {
    unsigned r;
    asm("v_cvt_pk_bf16_f32 %0, %1, %2" : "=v"(r) : "v"(lo), "v"(hi));
    return r;
}

// async global->LDS, 16B per lane; lds base wave-uniform (lane i -> base + i*16)
__device__ __forceinline__ void gl2lds16(const unsigned short* g, unsigned short* l) {
    __builtin_amdgcn_global_load_lds(
        (const __attribute__((address_space(1))) unsigned int*)g,
        (__attribute__((address_space(3))) unsigned int*)l,
        16, 0, 0);
}

// ---------------- Kernel 0: router only (RMSNorm + softmax top-2) ----------------
// 512 blocks x 256 threads; one token per wave.
__global__ __launch_bounds__(256) void k_prep5(
        const float* __restrict__ x,
        const float* __restrict__ g,
        const float* __restrict__ gate_w,
        unsigned short* __restrict__ x_norm,
        int* __restrict__ counts,
        int* __restrict__ slot_token,
        float* __restrict__ slot_prob,
        int* __restrict__ tslot) {
    int tid = threadIdx.x;
    int lane = tid & 63;
    int token = blockIdx.x * 4 + (tid >> 6);
    const float* xrow = x + (size_t)token * DDIM;

    float v[16];
    float ss = 0.f;
    #pragma unroll
    for (int i = 0; i < 16; i++) {
        float t = xrow[lane + i * 64];
        v[i] = t;
        ss += t * t;
    }
    #pragma unroll
    for (int o = 32; o > 0; o >>= 1) ss += __shfl_down(ss, o, 64);
    float scale = rsqrtf(__shfl(ss, 0, 64) * (1.f / (float)DDIM) + EPS_RMS);

    float part[NE];
    #pragma unroll
    for (int e = 0; e < NE; e++) part[e] = 0.f;
    #pragma unroll
    for (int i = 0; i < 16; i++) {
        int d = lane + i * 64;
        float xn = v[i] * scale * g[d];
        x_norm[(size_t)token * DDIM + d] = f2bf(xn);
        #pragma unroll
        for (int e = 0; e < NE; e++) part[e] += xn * gate_w[e * DDIM + d];
    }
    #pragma unroll
    for (int e = 0; e < NE; e++) {
        #pragma unroll
        for (int o = 32; o > 0; o >>= 1) part[e] += __shfl_down(part[e], o, 64);
    }

    if (lane == 0) {
        float mx = part[0];
        #pragma unroll
        for (int e = 1; e < NE; e++) mx = fmaxf(mx, part[e]);
        float p[NE];
        float Z = 0.f;
        #pragma unroll
        for (int e = 0; e < NE; e++) { p[e] = __expf(part[e] - mx); Z += p[e]; }
        float rz = 1.f / Z;
        #pragma unroll
        for (int e = 0; e < NE; e++) p[e] *= rz;
        int i1 = 0;
        #pragma unroll
        for (int e = 1; e < NE; e++) if (p[e] > p[i1]) i1 = e;
        int i2 = -1;
        #pragma unroll
        for (int e = 0; e < NE; e++) {
            if (e == i1) continue;
            if (i2 < 0 || p[e] > p[i2]) i2 = e;
        }
        float denom = p[i1] + p[i2] + EPS_TOPK;
        int pos1 = atomicAdd(&counts[i1], 1);
        slot_token[i1 * NTOK + pos1] = token;
        slot_prob[i1 * NTOK + pos1] = p[i1] / denom;
        tslot[token * 2 + 0] = i1 * NTOK + pos1;
        int pos2 = atomicAdd(&counts[i2], 1);
        slot_token[i2 * NTOK + pos2] = token;
        slot_prob[i2 * NTOK + pos2] = p[i2] / denom;
        tslot[token * 2 + 1] = i2 * NTOK + pos2;
    }
}

// map flat m-tile t (over concatenated slot array) -> (expert e, tile-local m0,
// slot offset off). Returns false if t beyond the last tile.
__device__ __forceinline__ bool flat_tile(const int* counts, int t,
                                          int& e, int& m0, int& off, int& cnt) {
    off = 0;
    for (e = 0; e < NE; e++) {
        cnt = counts[e];
        int nt = (cnt + 127) >> 7;
        if (t < nt) { m0 = t * 128; return true; }
        t -= nt;
        off += cnt;
    }
    return false;
}

// ---------------- Kernel 2: gathered GEMM X @ [W1|W2] (fp32 weights DIRECT) + SiLU ----------------
// bid < NGEMM: GEMM block (128x128, 4 waves 2x2). B staged from RAW fp32 w1/w2:
//   per K-step each thread: 16 coalesced scalar fp32 loads (one h-col, 8 d x 2 mats)
//   -> v_cvt_pk_bf16_f32 -> 2x ds_write_b128 into Bsh (row stride 40 u16 = 80B:
//   16B-aligned b128, writes tile all 32 banks, fragment reads 2-way).
//   This DELETES the w1/w2 conversion prepass (~87us + 190MB round-trip).
// bid >= NGEMM: w3 -> w3_blk conversion block (no dependency on GEMM output;
//   backfills CUs during GEMM drain; must finish by kernel end for k_ffn_out).
__global__ __launch_bounds__(256) void k_ffn_h5(
        const unsigned short* __restrict__ x_norm,  // bf16 [NTOK][1024]
        const float* __restrict__ w1,
        const float* __restrict__ w2,
        const float* __restrict__ w3,
        unsigned short* __restrict__ w3T,           // blocked [E][64][1024][32] bf16
        const int* __restrict__ counts,
        const int* __restrict__ slot_token,
        unsigned short* __restrict__ hidden) {      // bf16 [4096 slots][2048]
    __shared__ unsigned short smem[9472];           // 18944 B, unioned
    int tid = threadIdx.x;
    int bid = blockIdx.x;

    if (bid >= NGEMM) {
        // ---- w3 -> w3_blk (v4 code, verbatim logic) ----
        int idx = bid - NGEMM;
        int e    = idx >> 8;
        int hc   = (idx & 255) >> 2;
        int dsec = idx & 3;
        int h0 = hc * 32, d0 = dsec * 256;
        int wv = tid >> 6, l = tid & 63;
        unsigned short* sst = smem;   // [32][258] u16 = 8256 u16
        const float* b3 = w3 + (size_t)e * HDIM * DDIM + (size_t)h0 * DDIM + d0 + l * 4;
        float4 va[8];
        #pragma unroll
        for (int k = 0; k < 8; k++) va[k] = *(const float4*)(b3 + (size_t)(wv * 8 + k) * DDIM);
        #pragma unroll
        for (int k = 0; k < 8; k++) {
            int r = wv * 8 + k;
            unsigned* pa = (unsigned*)&sst[r * 258 + l * 4];
            pa[0] = pack2bf(va[k].x, va[k].y);
            pa[1] = pack2bf(va[k].z, va[k].w);
        }
        __syncthreads();
        size_t slab = (((size_t)e * 64 + hc) * 1024 + d0) * 32;
        int ul = tid & 3;
        #pragma unroll
        for (int j = 0; j < 4; j++) {
            int dl = j * 64 + (tid >> 2);
            uint4 W;
            unsigned short a0 = sst[(8 * ul + 0) * 258 + dl], a1 = sst[(8 * ul + 1) * 258 + dl];
            unsigned short a2 = sst[(8 * ul + 2) * 258 + dl], a3 = sst[(8 * ul + 3) * 258 + dl];
            unsigned short a4 = sst[(8 * ul + 4) * 258 + dl], a5 = sst[(8 * ul + 5) * 258 + dl];
            unsigned short a6 = sst[(8 * ul + 6) * 258 + dl], a7 = sst[(8 * ul + 7) * 258 + dl];
            W.x = (unsigned)a0 | ((unsigned)a1 << 16);
            W.y = (unsigned)a2 | ((unsigned)a3 << 16);
            W.z = (unsigned)a4 | ((unsigned)a5 << 16);
            W.w = (unsigned)a6 | ((unsigned)a7 << 16);
            *(uint4*)&w3T[slab + (size_t)dl * 32 + ul * 8] = W;
        }
        return;
    }

    // ---- GEMM block ----
    int xcd = bid & 7;
    int idx = bid >> 3;               // 0..159
    int nn = idx / MT_MAX;            // 0..3
    int mt = idx % MT_MAX;
    int n0 = (xcd * 4 + nn) * 128;
    int h_base = n0 >> 1;             // 64 h-cols per tile (x2 mats)

    int e, m0, off, cnt;
    if (!flat_tile(counts, mt, e, m0, off, cnt)) return;

    int lane = tid & 63, wv = tid >> 6;
    int l15 = lane & 15, q4 = lane >> 4;
    int wy = wv >> 1, wx = wv & 1;

    int* tok = (int*)smem;                        // 128 ints
    unsigned short* Ash = smem + 256;             // [128][32] linear (gload_lds)
    unsigned short* Bsh = smem + 256 + 4096;      // [128][40] padded (byte base 8704, 16B-aligned)

    if (tid < 128) {
        int i = m0 + tid;
        tok[tid] = (i < cnt) ? slot_token[e * NTOK + i] : slot_token[e * NTOK];
    }
    __syncthreads();

    int arow = wv * 32 + (lane >> 2);
    int t0 = tok[arow];
    int t1 = tok[arow + 16];
    const unsigned short* ag0 = x_norm + (size_t)t0 * DDIM + (lane & 3) * 8;
    const unsigned short* ag1 = x_norm + (size_t)t1 * DDIM + (lane & 3) * 8;
    unsigned short* alds = &Ash[wv * 1024];

    // B-staging mapping: thread = (hl 0..63, dg 0..3)
    int hl = tid & 63;
    int dg = tid >> 6;
    int n1 = ((hl >> 5) << 6) + (hl & 31);     // w1 row in tile
    int n2 = n1 + 32;                          // w2 row
    const float* w1p = w1 + (size_t)e * DDIM * HDIM + (h_base + hl);
    const float* w2p = w2 + (size_t)e * DDIM * HDIM + (h_base + hl);
    unsigned short* bw1 = &Bsh[n1 * 40 + dg * 8];
    unsigned short* bw2 = &Bsh[n2 * 40 + dg * 8];

    f32x4 acc[4][4];
    #pragma unroll
    for (int i = 0; i < 4; i++)
        #pragma unroll
        for (int j = 0; j < 4; j++) acc[i][j] = (f32x4){0.f, 0.f, 0.f, 0.f};

    for (int d0 = 0; d0 < DDIM; d0 += 32) {
        // issue B fp32 loads into regs BEFORE the barrier (latency hides under
        // the other waves' compute + barrier wait)
        int db = d0 + dg * 8;
        float a1[8], a2[8];
        #pragma unroll
        for (int k = 0; k < 8; k++) a1[k] = w1p[(size_t)(db + k) * HDIM];
        #pragma unroll
        for (int k = 0; k < 8; k++) a2[k] = w2p[(size_t)(db + k) * HDIM];

        __syncthreads();   // prev iteration's fragment reads done -> safe to overwrite LDS
        gl2lds16(ag0 + d0, alds);
        gl2lds16(ag1 + d0, alds + 512);
        uint4 W1, W2;
        W1.x = cvtpk(a1[0], a1[1]); W1.y = cvtpk(a1[2], a1[3]);
        W1.z = cvtpk(a1[4], a1[5]); W1.w = cvtpk(a1[6], a1[7]);
        W2.x = cvtpk(a2[0], a2[1]); W2.y = cvtpk(a2[2], a2[3]);
        W2.z = cvtpk(a2[4], a2[5]); W2.w = cvtpk(a2[6], a2[7]);
        *(uint4*)bw1 = W1;
        *(uint4*)bw2 = W2;
        __syncthreads();   // stage visible (vmcnt0 + lgkmcnt0 drained by barrier)

        short8 af[4], bf[4];
        #pragma unroll
        for (int i = 0; i < 4; i++) {
            af[i] = *(const short8*)&Ash[(wy * 64 + i * 16 + l15) * 32 + q4 * 8];
            bf[i] = *(const short8*)&Bsh[(wx * 64 + i * 16 + l15) * 40 + q4 * 8];
        }
        #pragma unroll
        for (int rf = 0; rf < 4; rf++)
            #pragma unroll
            for (int cf = 0; cf < 4; cf++)
                acc[rf][cf] = __builtin_amdgcn_mfma_f32_16x16x32_bf16(af[rf], bf[cf], acc[rf][cf], 0, 0, 0);
    }

    // epilogue: cf 0,1 = w1 cols, cf 2,3 = w2 cols for the same h
    #pragma unroll
    for (int rf = 0; rf < 4; rf++) {
        int rowl = wy * 64 + rf * 16 + q4 * 4;
        #pragma unroll
        for (int hg = 0; hg < 2; hg++) {
            int h = h_base + wx * 32 + hg * 16 + l15;
            #pragma unroll
            for (int r = 0; r < 4; r++) {
                int rr = rowl + r;
                if (m0 + rr < cnt) {
                    float a = acc[rf][hg][r];
                    float b = acc[rf][hg + 2][r];
                    float hv = (a / (1.f + __expf(-a))) * b;
                    hidden[(size_t)(off + m0 + rr) * HDIM + h] = f2bf(hv);
                }
            }
        }
    }
}

// ---------------- Kernel 3: GEMM hidden @ w3_blk, K-split ----------------
// 1-D grid 8*2*MT_MAX = 640. xcd = bid&7 owns d-tile xcd.
__global__ __launch_bounds__(256) void k_ffn_out(
        const unsigned short* __restrict__ hidden,  // bf16 [4096][2048]
        const unsigned short* __restrict__ w3T,     // blocked [E][64][1024][32]
        const int* __restrict__ counts,
        float* __restrict__ yp) {                   // [KSPLIT][4096][1024] f32 partials
    int bid = blockIdx.x;
    int xcd = bid & 7;
    int idx = bid >> 3;               // 0..79
    int ks = idx / MT_MAX;            // 0..1
    int mt = idx % MT_MAX;
    int d0 = xcd * 128;

    int e, m0, off, cnt;
    if (!flat_tile(counts, mt, e, m0, off, cnt)) return;
    int hb = ks * KCH;

    int tid = threadIdx.x, lane = tid & 63, wv = tid >> 6;
    int l15 = lane & 15, q4 = lane >> 4;
    int wy = wv >> 1, wx = wv & 1;

    __shared__ unsigned short Ash[128 * 32];
    __shared__ unsigned short Bsh[128 * 32];

    int arow = wv * 32 + (lane >> 2);
    int s0 = off + ((m0 + arow < cnt) ? m0 + arow : 0);
    int s1 = off + ((m0 + arow + 16 < cnt) ? m0 + arow + 16 : 0);
    const unsigned short* ag0 = hidden + (size_t)s0 * HDIM + hb + (lane & 3) * 8;
    const unsigned short* ag1 = hidden + (size_t)s1 * HDIM + hb + (lane & 3) * 8;
    const unsigned short* bg0 = w3T + (((size_t)e * 64 + (hb >> 5)) * 1024 + (size_t)(d0 + arow)) * 32 + (lane & 3) * 8;
    const unsigned short* bg1 = bg0 + 16 * 32;
    unsigned short* alds = &Ash[wv * 1024];
    unsigned short* blds = &Bsh[wv * 1024];

    f32x4 acc[4][4];
    #pragma unroll
    for (int i = 0; i < 4; i++)
        #pragma unroll
        for (int j = 0; j < 4; j++) acc[i][j] = (f32x4){0.f, 0.f, 0.f, 0.f};

    for (int h0 = 0; h0 < KCH; h0 += 32) {
        __syncthreads();
        gl2lds16(ag0 + h0, alds);
        gl2lds16(ag1 + h0, alds + 512);
        gl2lds16(bg0, blds);
        gl2lds16(bg1, blds + 512);
        bg0 += 1024 * 32;   // next h-chunk slab
        bg1 += 1024 * 32;
        __syncthreads();

        short8 af[4], bf[4];
        #pragma unroll
        for (int i = 0; i < 4; i++) {
            af[i] = *(const short8*)&Ash[(wy * 64 + i * 16 + l15) * 32 + q4 * 8];
            bf[i] = *(const short8*)&Bsh[(wx * 64 + i * 16 + l15) * 32 + q4 * 8];
        }
        #pragma unroll
        for (int rf = 0; rf < 4; rf++)
            #pragma unroll
            for (int cf = 0; cf < 4; cf++)
                acc[rf][cf] = __builtin_amdgcn_mfma_f32_16x16x32_bf16(af[rf], bf[cf], acc[rf][cf], 0, 0, 0);
    }

    float* ypk = yp + (size_t)ks * 4096 * 1024;
    #pragma unroll
    for (int rf = 0; rf < 4; rf++) {
        int rowl = wy * 64 + rf * 16 + q4 * 4;
        #pragma unroll
        for (int cf = 0; cf < 4; cf++) {
            int col = d0 + wx * 64 + cf * 16 + l15;
            #pragma unroll
            for (int r = 0; r < 4; r++) {
                int rr = rowl + r;
                if (m0 + rr < cnt) {
                    ypk[(size_t)(off + m0 + rr) * 1024 + col] = acc[rf][cf][r];
                }
            }
        }
    }
}

// ---------------- Kernel 4: gather partials -> out ----------------
__global__ __launch_bounds__(256) void k_gather(
        const float* __restrict__ yp,         // [KSPLIT][4096][1024]
        const int* __restrict__ counts,
        const int* __restrict__ tslot,
        const float* __restrict__ slot_prob,
        float* __restrict__ out) {
    __shared__ int offs[NE];
    int tid = threadIdx.x;
    if (tid < NE) {
        int o = 0;
        for (int i = 0; i < tid; i++) o += counts[i];
        offs[tid] = o;
    }
    __syncthreads();

    int token = blockIdx.x * 2 + (tid >> 7);
    int col = (tid & 127) * 8;

    int s0 = tslot[token * 2], s1 = tslot[token * 2 + 1];
    int g0 = offs[s0 / NTOK] + (s0 % NTOK);
    int g1 = offs[s1 / NTOK] + (s1 % NTOK);
    float pr0 = slot_prob[s0], pr1 = slot_prob[s1];

    const float* p00 = yp + (size_t)g0 * 1024 + col;
    const float* p01 = yp + (size_t)(4096 + g0) * 1024 + col;
    const float* p10 = yp + (size_t)g1 * 1024 + col;
    const float* p11 = yp + (size_t)(4096 + g1) * 1024 + col;
    float* op = out + (size_t)token * 1024 + col;

    #pragma unroll
    for (int v = 0; v < 2; v++) {
        float4 a0 = *(const float4*)(p00 + v * 4);
        float4 a1 = *(const float4*)(p01 + v * 4);
        float4 b0 = *(const float4*)(p10 + v * 4);
        float4 b1 = *(const float4*)(p11 + v * 4);
        float4 r;
        r.x = pr0 * (a0.x + a1.x) + pr1 * (b0.x + b1.x);
        r.y = pr0 * (a0.y + a1.y) + pr1 * (b0.y + b1.y);
        r.z = pr0 * (a0.z + a1.z) + pr1 * (b0.z + b1.z);
        r.w = pr0 * (a0.w + a1.w) + pr1 * (b0.w + b1.w);
        *(float4*)(op + v * 4) = r;
    }
}

// ---------------- launch ----------------
extern "C" void kernel_launch(void* const* d_in, const int* in_sizes, int n_in,
                              void* d_out, int out_size, void* d_ws, size_t ws_size,
                              hipStream_t stream) {
    const float* x      = (const float*)d_in[0];
    const float* g      = (const float*)d_in[1];
    const float* gate_w = (const float*)d_in[2];
    const float* w1     = (const float*)d_in[3];
    const float* w2     = (const float*)d_in[4];
    const float* w3     = (const float*)d_in[5];
    float* out = (float*)d_out;

    char* ws = (char*)d_ws;
    int*   counts     = (int*)ws;                 ws += 256;
    int*   slot_token = (int*)ws;                 ws += NE * NTOK * 4;
    float* slot_prob  = (float*)ws;               ws += NE * NTOK * 4;
    int*   tslot      = (int*)ws;                 ws += NTOK * 2 * 4;
    unsigned short* x_norm = (unsigned short*)ws; ws += (size_t)NTOK * DDIM * 2;           // 4 MB
    unsigned short* hidden = (unsigned short*)ws; ws += (size_t)NTOK * 2 * HDIM * 2;       // 16 MB
    unsigned short* w3T    = (unsigned short*)ws; ws += (size_t)NE * 1024 * 2048 * 2;      // 32 MB (blocked)
    float* yp              = (float*)ws;          ws += (size_t)KSPLIT * 4096 * 1024 * 4;  // 32 MB

    hipMemsetAsync(counts, 0, 256, stream);

    // router only (~10us)
    k_prep5<<<dim3(512), 256, 0, stream>>>(x, g, gate_w, x_norm,
                                           counts, slot_token, slot_prob, tslot);

    // fused GEMM (fp32 weights direct) + w3-conversion blocks in one grid
    k_ffn_h5<<<dim3(NGEMM + 2048), 256, 0, stream>>>(
        x_norm, w1, w2, w3, w3T, counts, slot_token, hidden);

    k_ffn_out<<<dim3(8 * 2 * MT_MAX), 256, 0, stream>>>(hidden, w3T, counts, yp);

    k_gather<<<NTOK / 2, 256, 0, stream>>>(yp, counts, tslot, slot_prob, out);
}

// Round 7
// 357.251 us; speedup vs baseline: 1.0926x; 1.0736x over previous
//
#include <hip/hip_runtime.h>
#include <math.h>

#define NTOK 2048      // B*S
#define DDIM 1024
#define HDIM 2048
#define NE 8
#define EPS_RMS 1e-5f
#define EPS_TOPK 1e-10f

#define KSPLIT 2
#define KCH (HDIM / KSPLIT)   // 1024

// flat m-tiles over the concatenated slot array (always exactly 4096 slots);
// worst case sum_e ceil(cnt_e/128) <= 32 + 7 = 39
#define MT_MAX 40
#define NGEMM (8 * 4 * MT_MAX)   // 1280 GEMM blocks in k_ffn_h6

typedef short short8 __attribute__((ext_vector_type(8)));
typedef float f32x4  __attribute__((ext_vector_type(4)));

__device__ __forceinline__ unsigned pack2bf(float a, float b) {
    unsigned ua = __builtin_bit_cast(unsigned, a);
    unsigned ub = __builtin_bit_cast(unsigned, b);
    ua = (ua + 0x7fffu + ((ua >> 16) & 1u)) >> 16;
    ub = (ub + 0x7fffu + ((ub >> 16) & 1u)) & 0xffff0000u;
    return ua | ub;
}
__device__ __forceinline__ unsigned short f2bf(float a) {
    unsigned ua = __builtin_bit_cast(unsigned, a);
    return (unsigned short)((ua + 0x7fffu + ((ua >> 16) & 1u)) >> 16);
}
// hw packed fp32x2 -> bf16x2 (RNE)
__device__ __forceinline__ unsigned cvtpk(float lo, float hi) {
    unsigned r;
    asm("v_cvt_pk_bf16_f32 %0, %1, %2" : "=v"(r) : "v"(lo), "v"(hi));
    return r;
}

// ---------------- Kernel 0: router only (RMSNorm + softmax top-2) ----------------
__global__ __launch_bounds__(256) void k_prep5(
        const float* __restrict__ x,
        const float* __restrict__ g,
        const float* __restrict__ gate_w,
        unsigned short* __restrict__ x_norm,
        int* __restrict__ counts,
        int* __restrict__ slot_token,
        float* __restrict__ slot_prob,
        int* __restrict__ tslot) {
    int tid = threadIdx.x;
    int lane = tid & 63;
    int token = blockIdx.x * 4 + (tid >> 6);
    const float* xrow = x + (size_t)token * DDIM;

    float v[16];
    float ss = 0.f;
    #pragma unroll
    for (int i = 0; i < 16; i++) {
        float t = xrow[lane + i * 64];
        v[i] = t;
        ss += t * t;
    }
    #pragma unroll
    for (int o = 32; o > 0; o >>= 1) ss += __shfl_down(ss, o, 64);
    float scale = rsqrtf(__shfl(ss, 0, 64) * (1.f / (float)DDIM) + EPS_RMS);

    float part[NE];
    #pragma unroll
    for (int e = 0; e < NE; e++) part[e] = 0.f;
    #pragma unroll
    for (int i = 0; i < 16; i++) {
        int d = lane + i * 64;
        float xn = v[i] * scale * g[d];
        x_norm[(size_t)token * DDIM + d] = f2bf(xn);
        #pragma unroll
        for (int e = 0; e < NE; e++) part[e] += xn * gate_w[e * DDIM + d];
    }
    #pragma unroll
    for (int e = 0; e < NE; e++) {
        #pragma unroll
        for (int o = 32; o > 0; o >>= 1) part[e] += __shfl_down(part[e], o, 64);
    }

    if (lane == 0) {
        float mx = part[0];
        #pragma unroll
        for (int e = 1; e < NE; e++) mx = fmaxf(mx, part[e]);
        float p[NE];
        float Z = 0.f;
        #pragma unroll
        for (int e = 0; e < NE; e++) { p[e] = __expf(part[e] - mx); Z += p[e]; }
        float rz = 1.f / Z;
        #pragma unroll
        for (int e = 0; e < NE; e++) p[e] *= rz;
        int i1 = 0;
        #pragma unroll
        for (int e = 1; e < NE; e++) if (p[e] > p[i1]) i1 = e;
        int i2 = -1;
        #pragma unroll
        for (int e = 0; e < NE; e++) {
            if (e == i1) continue;
            if (i2 < 0 || p[e] > p[i2]) i2 = e;
        }
        float denom = p[i1] + p[i2] + EPS_TOPK;
        int pos1 = atomicAdd(&counts[i1], 1);
        slot_token[i1 * NTOK + pos1] = token;
        slot_prob[i1 * NTOK + pos1] = p[i1] / denom;
        tslot[token * 2 + 0] = i1 * NTOK + pos1;
        int pos2 = atomicAdd(&counts[i2], 1);
        slot_token[i2 * NTOK + pos2] = token;
        slot_prob[i2 * NTOK + pos2] = p[i2] / denom;
        tslot[token * 2 + 1] = i2 * NTOK + pos2;
    }
}

__device__ __forceinline__ bool flat_tile(const int* counts, int t,
                                          int& e, int& m0, int& off, int& cnt) {
    off = 0;
    for (e = 0; e < NE; e++) {
        cnt = counts[e];
        int nt = (cnt + 127) >> 7;
        if (t < nt) { m0 = t * 128; return true; }
        t -= nt;
        off += cnt;
    }
    return false;
}

// ---------------- Kernel 2: gathered GEMM X @ [W1|W2] (fp32 direct) + SiLU, T14 pipeline ----------------
// Per K-step: barrier -> write LDS from regs(t) -> issue reg loads(t+1) -> barrier -> compute(t).
// Loads for t+1 hide under compute(t)'s MFMA+ds_read phase (r6 had them fully exposed:
// MfmaUtil 11.5%, 135us at only 135MB FETCH).
__global__ __launch_bounds__(256) void k_ffn_h6(
        const unsigned short* __restrict__ x_norm,  // bf16 [NTOK][1024]
        const float* __restrict__ w1,
        const float* __restrict__ w2,
        const float* __restrict__ w3,
        unsigned short* __restrict__ w3T,           // blocked [E][64][1024][32] bf16
        const int* __restrict__ counts,
        const int* __restrict__ slot_token,
        unsigned short* __restrict__ hidden) {      // bf16 [4096 slots][2048]
    __shared__ unsigned short smem[9472];           // 18944 B: tok 512B | Ash 8KB | Bsh 10240B
    int tid = threadIdx.x;
    int bid = blockIdx.x;

    if (bid >= NGEMM) {
        // ---- w3 -> w3_blk conversion (unchanged) ----
        int idx = bid - NGEMM;
        int e    = idx >> 8;
        int hc   = (idx & 255) >> 2;
        int dsec = idx & 3;
        int h0 = hc * 32, d0 = dsec * 256;
        int wv = tid >> 6, l = tid & 63;
        unsigned short* sst = smem;   // [32][258] u16
        const float* b3 = w3 + (size_t)e * HDIM * DDIM + (size_t)h0 * DDIM + d0 + l * 4;
        float4 va[8];
        #pragma unroll
        for (int k = 0; k < 8; k++) va[k] = *(const float4*)(b3 + (size_t)(wv * 8 + k) * DDIM);
        #pragma unroll
        for (int k = 0; k < 8; k++) {
            int r = wv * 8 + k;
            unsigned* pa = (unsigned*)&sst[r * 258 + l * 4];
            pa[0] = pack2bf(va[k].x, va[k].y);
            pa[1] = pack2bf(va[k].z, va[k].w);
        }
        __syncthreads();
        size_t slab = (((size_t)e * 64 + hc) * 1024 + d0) * 32;
        int ul = tid & 3;
        #pragma unroll
        for (int j = 0; j < 4; j++) {
            int dl = j * 64 + (tid >> 2);
            uint4 W;
            unsigned short a0 = sst[(8 * ul + 0) * 258 + dl], a1 = sst[(8 * ul + 1) * 258 + dl];
            unsigned short a2 = sst[(8 * ul + 2) * 258 + dl], a3 = sst[(8 * ul + 3) * 258 + dl];
            unsigned short a4 = sst[(8 * ul + 4) * 258 + dl], a5 = sst[(8 * ul + 5) * 258 + dl];
            unsigned short a6 = sst[(8 * ul + 6) * 258 + dl], a7 = sst[(8 * ul + 7) * 258 + dl];
            W.x = (unsigned)a0 | ((unsigned)a1 << 16);
            W.y = (unsigned)a2 | ((unsigned)a3 << 16);
            W.z = (unsigned)a4 | ((unsigned)a5 << 16);
            W.w = (unsigned)a6 | ((unsigned)a7 << 16);
            *(uint4*)&w3T[slab + (size_t)dl * 32 + ul * 8] = W;
        }
        return;
    }

    // ---- GEMM block ----
    int xcd = bid & 7;
    int idx = bid >> 3;
    int nn = idx / MT_MAX;
    int mt = idx % MT_MAX;
    int n0 = (xcd * 4 + nn) * 128;
    int h_base = n0 >> 1;

    int e, m0, off, cnt;
    if (!flat_tile(counts, mt, e, m0, off, cnt)) return;

    int lane = tid & 63, wv = tid >> 6;
    int l15 = lane & 15, q4 = lane >> 4;
    int wy = wv >> 1, wx = wv & 1;

    int* tok = (int*)smem;                        // 128 ints
    unsigned short* Ash = smem + 256;             // [128][32] linear
    unsigned short* Bsh = smem + 256 + 4096;      // [128][40] padded (byte 8704, 16B-aligned)

    if (tid < 128) {
        int i = m0 + tid;
        tok[tid] = (i < cnt) ? slot_token[e * NTOK + i] : slot_token[e * NTOK];
    }
    __syncthreads();

    // A reg-stage mapping: u in {0,1}: idx=tid+u*256 -> row=idx>>2, q=idx&3
    int rA0 = tid >> 2,        qA0 = tid & 3;
    int rA1 = (tid + 256) >> 2, qA1 = tid & 3;
    const unsigned short* ap0 = x_norm + (size_t)tok[rA0] * DDIM + qA0 * 8;
    const unsigned short* ap1 = x_norm + (size_t)tok[rA1] * DDIM + qA1 * 8;
    unsigned short* aw0 = &Ash[rA0 * 32 + qA0 * 8];
    unsigned short* aw1 = &Ash[rA1 * 32 + qA1 * 8];

    // B staging mapping (fp32 direct): thread = (hl 0..63, dg 0..3)
    int hl = tid & 63;
    int dg = tid >> 6;
    int n1 = ((hl >> 5) << 6) + (hl & 31);
    int n2 = n1 + 32;
    const float* w1p = w1 + (size_t)e * DDIM * HDIM + (h_base + hl);
    const float* w2p = w2 + (size_t)e * DDIM * HDIM + (h_base + hl);
    unsigned short* bw1 = &Bsh[n1 * 40 + dg * 8];
    unsigned short* bw2 = &Bsh[n2 * 40 + dg * 8];

    f32x4 acc[4][4];
    #pragma unroll
    for (int i = 0; i < 4; i++)
        #pragma unroll
        for (int j = 0; j < 4; j++) acc[i][j] = (f32x4){0.f, 0.f, 0.f, 0.f};

    // prologue: load regs for step 0
    uint4 ra0 = *(const uint4*)ap0;
    uint4 ra1 = *(const uint4*)ap1;
    float a1r[8], a2r[8];
    #pragma unroll
    for (int k = 0; k < 8; k++) a1r[k] = w1p[(size_t)(dg * 8 + k) * HDIM];
    #pragma unroll
    for (int k = 0; k < 8; k++) a2r[k] = w2p[(size_t)(dg * 8 + k) * HDIM];

    for (int it = 0; it < 32; ++it) {
        __syncthreads();   // compute(it-1) done -> LDS free
        // write stage(it) from regs (compiler inserts vmcnt wait at use)
        *(uint4*)aw0 = ra0;
        *(uint4*)aw1 = ra1;
        uint4 W1, W2;
        W1.x = cvtpk(a1r[0], a1r[1]); W1.y = cvtpk(a1r[2], a1r[3]);
        W1.z = cvtpk(a1r[4], a1r[5]); W1.w = cvtpk(a1r[6], a1r[7]);
        W2.x = cvtpk(a2r[0], a2r[1]); W2.y = cvtpk(a2r[2], a2r[3]);
        W2.z = cvtpk(a2r[4], a2r[5]); W2.w = cvtpk(a2r[6], a2r[7]);
        *(uint4*)bw1 = W1;
        *(uint4*)bw2 = W2;
        // issue loads for step it+1 (hidden under compute below)
        if (it < 31) {
            int d0n = (it + 1) * 32;
            ra0 = *(const uint4*)(ap0 + d0n);
            ra1 = *(const uint4*)(ap1 + d0n);
            int db = d0n + dg * 8;
            #pragma unroll
            for (int k = 0; k < 8; k++) a1r[k] = w1p[(size_t)(db + k) * HDIM];
            #pragma unroll
            for (int k = 0; k < 8; k++) a2r[k] = w2p[(size_t)(db + k) * HDIM];
        }
        __syncthreads();   // stage visible
        // compute(it)
        short8 af[4], bf[4];
        #pragma unroll
        for (int i = 0; i < 4; i++) {
            af[i] = *(const short8*)&Ash[(wy * 64 + i * 16 + l15) * 32 + q4 * 8];
            bf[i] = *(const short8*)&Bsh[(wx * 64 + i * 16 + l15) * 40 + q4 * 8];
        }
        #pragma unroll
        for (int rf = 0; rf < 4; rf++)
            #pragma unroll
            for (int cf = 0; cf < 4; cf++)
                acc[rf][cf] = __builtin_amdgcn_mfma_f32_16x16x32_bf16(af[rf], bf[cf], acc[rf][cf], 0, 0, 0);
    }

    // epilogue: cf 0,1 = w1 cols, cf 2,3 = w2 cols for the same h
    #pragma unroll
    for (int rf = 0; rf < 4; rf++) {
        int rowl = wy * 64 + rf * 16 + q4 * 4;
        #pragma unroll
        for (int hg = 0; hg < 2; hg++) {
            int h = h_base + wx * 32 + hg * 16 + l15;
            #pragma unroll
            for (int r = 0; r < 4; r++) {
                int rr = rowl + r;
                if (m0 + rr < cnt) {
                    float a = acc[rf][hg][r];
                    float b = acc[rf][hg + 2][r];
                    float hv = (a / (1.f + __expf(-a))) * b;
                    hidden[(size_t)(off + m0 + rr) * HDIM + h] = f2bf(hv);
                }
            }
        }
    }
}

// ---------------- Kernel 3: GEMM hidden @ w3_blk, K-split, T14 pipeline ----------------
__global__ __launch_bounds__(256) void k_ffn_out6(
        const unsigned short* __restrict__ hidden,  // bf16 [4096][2048]
        const unsigned short* __restrict__ w3T,     // blocked [E][64][1024][32]
        const int* __restrict__ counts,
        float* __restrict__ yp) {                   // [KSPLIT][4096][1024] f32 partials
    int bid = blockIdx.x;
    int xcd = bid & 7;
    int idx = bid >> 3;
    int ks = idx / MT_MAX;
    int mt = idx % MT_MAX;
    int d0 = xcd * 128;

    int e, m0, off, cnt;
    if (!flat_tile(counts, mt, e, m0, off, cnt)) return;
    int hb = ks * KCH;

    int tid = threadIdx.x, lane = tid & 63, wv = tid >> 6;
    int l15 = lane & 15, q4 = lane >> 4;
    int wy = wv >> 1, wx = wv & 1;

    __shared__ unsigned short Ash[128 * 32];
    __shared__ unsigned short Bsh[128 * 32];

    // A reg-stage: u in {0,1}: idx=tid+u*256 -> row=idx>>2, q=idx&3
    int rA0 = tid >> 2,         qA0 = tid & 3;
    int rA1 = (tid + 256) >> 2, qA1 = tid & 3;
    int s0 = off + ((m0 + rA0 < cnt) ? m0 + rA0 : 0);
    int s1 = off + ((m0 + rA1 < cnt) ? m0 + rA1 : 0);
    const unsigned short* ap0 = hidden + (size_t)s0 * HDIM + hb + qA0 * 8;
    const unsigned short* ap1 = hidden + (size_t)s1 * HDIM + hb + qA1 * 8;
    unsigned short* aw0 = &Ash[rA0 * 32 + qA0 * 8];
    unsigned short* aw1 = &Ash[rA1 * 32 + qA1 * 8];

    // B reg-stage: contiguous slab, thread covers idx*8 u16 (fully coalesced)
    const unsigned short* bbase = w3T + (((size_t)e * 64 + (hb >> 5)) * 1024 + d0) * 32;
    const unsigned short* bp0 = bbase + (size_t)tid * 8;
    const unsigned short* bp1 = bbase + (size_t)(tid + 256) * 8;
    unsigned short* bw0 = &Bsh[tid * 8];
    unsigned short* bw1 = &Bsh[(tid + 256) * 8];

    f32x4 acc[4][4];
    #pragma unroll
    for (int i = 0; i < 4; i++)
        #pragma unroll
        for (int j = 0; j < 4; j++) acc[i][j] = (f32x4){0.f, 0.f, 0.f, 0.f};

    // prologue
    uint4 ra0 = *(const uint4*)ap0;
    uint4 ra1 = *(const uint4*)ap1;
    uint4 rb0 = *(const uint4*)bp0;
    uint4 rb1 = *(const uint4*)bp1;

    for (int it = 0; it < 32; ++it) {
        __syncthreads();
        *(uint4*)aw0 = ra0;
        *(uint4*)aw1 = ra1;
        *(uint4*)bw0 = rb0;
        *(uint4*)bw1 = rb1;
        if (it < 31) {
            int h0n = (it + 1) * 32;
            ra0 = *(const uint4*)(ap0 + h0n);
            ra1 = *(const uint4*)(ap1 + h0n);
            const unsigned short* bs = bbase + (size_t)(it + 1) * 1024 * 32;
            rb0 = *(const uint4*)(bs + (size_t)tid * 8);
            rb1 = *(const uint4*)(bs + (size_t)(tid + 256) * 8);
        }
        __syncthreads();
        short8 af[4], bf[4];
        #pragma unroll
        for (int i = 0; i < 4; i++) {
            af[i] = *(const short8*)&Ash[(wy * 64 + i * 16 + l15) * 32 + q4 * 8];
            bf[i] = *(const short8*)&Bsh[(wx * 64 + i * 16 + l15) * 32 + q4 * 8];
        }
        #pragma unroll
        for (int rf = 0; rf < 4; rf++)
            #pragma unroll
            for (int cf = 0; cf < 4; cf++)
                acc[rf][cf] = __builtin_amdgcn_mfma_f32_16x16x32_bf16(af[rf], bf[cf], acc[rf][cf], 0, 0, 0);
    }

    float* ypk = yp + (size_t)ks * 4096 * 1024;
    #pragma unroll
    for (int rf = 0; rf < 4; rf++) {
        int rowl = wy * 64 + rf * 16 + q4 * 4;
        #pragma unroll
        for (int cf = 0; cf < 4; cf++) {
            int col = d0 + wx * 64 + cf * 16 + l15;
            #pragma unroll
            for (int r = 0; r < 4; r++) {
                int rr = rowl + r;
                if (m0 + rr < cnt) {
                    ypk[(size_t)(off + m0 + rr) * 1024 + col] = acc[rf][cf][r];
                }
            }
        }
    }
}

// ---------------- Kernel 4: gather partials -> out ----------------
__global__ __launch_bounds__(256) void k_gather(
        const float* __restrict__ yp,         // [KSPLIT][4096][1024]
        const int* __restrict__ counts,
        const int* __restrict__ tslot,
        const float* __restrict__ slot_prob,
        float* __restrict__ out) {
    __shared__ int offs[NE];
    int tid = threadIdx.x;
    if (tid < NE) {
        int o = 0;
        for (int i = 0; i < tid; i++) o += counts[i];
        offs[tid] = o;
    }
    __syncthreads();

    int token = blockIdx.x * 2 + (tid >> 7);
    int col = (tid & 127) * 8;

    int s0 = tslot[token * 2], s1 = tslot[token * 2 + 1];
    int g0 = offs[s0 / NTOK] + (s0 % NTOK);
    int g1 = offs[s1 / NTOK] + (s1 % NTOK);
    float pr0 = slot_prob[s0], pr1 = slot_prob[s1];

    const float* p00 = yp + (size_t)g0 * 1024 + col;
    const float* p01 = yp + (size_t)(4096 + g0) * 1024 + col;
    const float* p10 = yp + (size_t)g1 * 1024 + col;
    const float* p11 = yp + (size_t)(4096 + g1) * 1024 + col;
    float* op = out + (size_t)token * 1024 + col;

    #pragma unroll
    for (int v = 0; v < 2; v++) {
        float4 a0 = *(const float4*)(p00 + v * 4);
        float4 a1 = *(const float4*)(p01 + v * 4);
        float4 b0 = *(const float4*)(p10 + v * 4);
        float4 b1 = *(const float4*)(p11 + v * 4);
        float4 r;
        r.x = pr0 * (a0.x + a1.x) + pr1 * (b0.x + b1.x);
        r.y = pr0 * (a0.y + a1.y) + pr1 * (b0.y + b1.y);
        r.z = pr0 * (a0.z + a1.z) + pr1 * (b0.z + b1.z);
        r.w = pr0 * (a0.w + a1.w) + pr1 * (b0.w + b1.w);
        *(float4*)(op + v * 4) = r;
    }
}

// ---------------- launch ----------------
extern "C" void kernel_launch(void* const* d_in, const int* in_sizes, int n_in,
                              void* d_out, int out_size, void* d_ws, size_t ws_size,
                              hipStream_t stream) {
    const float* x      = (const float*)d_in[0];
    const float* g      = (const float*)d_in[1];
    const float* gate_w = (const float*)d_in[2];
    const float* w1     = (const float*)d_in[3];
    const float* w2     = (const float*)d_in[4];
    const float* w3     = (const float*)d_in[5];
    float* out = (float*)d_out;

    char* ws = (char*)d_ws;
    int*   counts     = (int*)ws;                 ws += 256;
    int*   slot_token = (int*)ws;                 ws += NE * NTOK * 4;
    float* slot_prob  = (float*)ws;               ws += NE * NTOK * 4;
    int*   tslot      = (int*)ws;                 ws += NTOK * 2 * 4;
    unsigned short* x_norm = (unsigned short*)ws; ws += (size_t)NTOK * DDIM * 2;           // 4 MB
    unsigned short* hidden = (unsigned short*)ws; ws += (size_t)NTOK * 2 * HDIM * 2;       // 16 MB
    unsigned short* w3T    = (unsigned short*)ws; ws += (size_t)NE * 1024 * 2048 * 2;      // 32 MB (blocked)
    float* yp              = (float*)ws;          ws += (size_t)KSPLIT * 4096 * 1024 * 4;  // 32 MB

    hipMemsetAsync(counts, 0, 256, stream);

    k_prep5<<<dim3(512), 256, 0, stream>>>(x, g, gate_w, x_norm,
                                           counts, slot_token, slot_prob, tslot);

    k_ffn_h6<<<dim3(NGEMM + 2048), 256, 0, stream>>>(
        x_norm, w1, w2, w3, w3T, counts, slot_token, hidden);

    k_ffn_out6<<<dim3(8 * 2 * MT_MAX), 256, 0, stream>>>(hidden, w3T, counts, yp);

    k_gather<<<NTOK / 2, 256, 0, stream>>>(yp, counts, tslot, slot_prob, out);
}